// Round 7
// baseline (919.683 us; speedup 1.0000x reference)
//
#include <hip/hip_runtime.h>

// EncoderBlock: B=8, S=2048, D=1024, H=4096, single-head attn (scale AFTER softmax),
// LN -> QKV -> scores -> softmax*(1/32) -> PV -> MLP(Swish) -> +residual.
// Round 7: pipelined-read 8-phase GEMM. Wave tile 64x128 (4M x 2N). Each phase:
//   BAR; lgkmcnt(0); [reads for NEXT phase, operand-disjoint]; stage; sched_barrier;
//   setprio(1); 16 MFMA; setprio(0); [vmcnt at P3/P7 end]
// LDS reads overlap MFMA execution (prior serialization was the 29% MfmaUtil cap).
// WS = 190,840,832 B, layout identical to R6.

#define Bb_ 8
#define Ss_ 2048
#define Dd_ 1024
#define Hh_ 4096

typedef __bf16 bf16;
typedef _Float16 f16;
typedef __attribute__((ext_vector_type(8))) __bf16 bf16x8;
typedef __attribute__((ext_vector_type(8))) _Float16 f16x8;
typedef __attribute__((ext_vector_type(4))) __bf16 bf16x4;
typedef __attribute__((ext_vector_type(4))) float f32x4;

enum { EPI_QKV = 0, EPI_F16 = 1, EPI_AOS = 2, EPI_SWISH = 3, EPI_RESID = 4 };

__device__ __forceinline__ void gload16(const bf16* g, bf16* l) {
  __builtin_amdgcn_global_load_lds(
      (const __attribute__((address_space(1))) void*)g,
      (__attribute__((address_space(3))) void*)l, 16, 0, 0);
}

typedef const __attribute__((address_space(3))) bf16 cl_bf16;
__device__ __forceinline__ bf16x8 dsr128(const bf16* p) {
  bf16x8 r;
  asm volatile("ds_read_b128 %0, %1" : "=v"(r) : "v"((cl_bf16*)p));
  return r;
}

#define BAR() __builtin_amdgcn_s_barrier()
#define LGKM0() asm volatile("s_waitcnt lgkmcnt(0)" ::: "memory")
#define LGKM4() asm volatile("s_waitcnt lgkmcnt(4)" ::: "memory")
#define VMC(n) asm volatile("s_waitcnt vmcnt(" #n ")" ::: "memory")
#define SCHED0() __builtin_amdgcn_sched_barrier(0)
#define SETP(x) __builtin_amdgcn_s_setprio(x)

// ---------- transpose-cast: W[K][N] f32 -> WT[N][K] bf16 ----------
__global__ __launch_bounds__(256) void tcast_k(const float* __restrict__ W,
                                               bf16* __restrict__ WT, int K, int N) {
  __shared__ float tile[32][33];
  const int tn0 = blockIdx.x * 32;
  const int tk0 = blockIdx.y * 32;
  const int t = threadIdx.x;
  const int c = t & 31;
  const int r4 = t >> 5;
#pragma unroll
  for (int i = 0; i < 4; i++) {
    int r = r4 + i * 8;
    tile[r][c] = W[(long)(tk0 + r) * N + (tn0 + c)];
  }
  __syncthreads();
#pragma unroll
  for (int i = 0; i < 4; i++) {
    int r = r4 + i * 8;
    WT[(long)(tn0 + r) * K + (tk0 + c)] = (bf16)tile[c][r];
  }
}

// ---------- fp16 transpose: v[z][2048][1024] -> vT[z][1024][2048] ----------
__global__ __launch_bounds__(256) void tbf16_k(const f16* __restrict__ V,
                                               f16* __restrict__ VT) {
  __shared__ f16 tile[64][72];
  const long z = blockIdx.z;
  const int n0 = blockIdx.x * 64;
  const int k0 = blockIdx.y * 64;
  const int t = threadIdx.x;
  const int r = t >> 3;
  const int c = (t & 7) * 8;
  const f16* Vb = V + z * (long)(Ss_ * Dd_);
  f16* VTb = VT + z * (long)(Dd_ * Ss_);
#pragma unroll
  for (int i = 0; i < 2; i++)
    *(f16x8*)&tile[r + i * 32][c] =
        *(const f16x8*)(Vb + (long)(k0 + r + i * 32) * Dd_ + n0 + c);
  __syncthreads();
#pragma unroll
  for (int i = 0; i < 2; i++) {
    const int n = r + i * 32;
    f16x8 ov;
#pragma unroll
    for (int j = 0; j < 8; j++) ov[j] = tile[c + j][n];
    *(f16x8*)(VTb + (long)(n0 + n) * Ss_ + k0 + c) = ov;
  }
}

// ---------- LayerNorm: x[row][1024] f32 -> xn bf16 ----------
__global__ __launch_bounds__(256) void ln_k(const float* __restrict__ x,
                                            const float* __restrict__ gamma,
                                            const float* __restrict__ beta,
                                            bf16* __restrict__ xn) {
  const long row = blockIdx.x;
  const float* xr = x + row * Dd_;
  const int t = threadIdx.x;
  float4 v = *(const float4*)(xr + t * 4);
  float s = v.x + v.y + v.z + v.w;
  float sq = v.x * v.x + v.y * v.y + v.z * v.z + v.w * v.w;
#pragma unroll
  for (int o = 32; o > 0; o >>= 1) {
    s += __shfl_down(s, o);
    sq += __shfl_down(sq, o);
  }
  __shared__ float ls[4], lq[4];
  const int wid = t >> 6;
  if ((t & 63) == 0) { ls[wid] = s; lq[wid] = sq; }
  __syncthreads();
  if (t == 0) {
    float S = ls[0] + ls[1] + ls[2] + ls[3];
    float Q = lq[0] + lq[1] + lq[2] + lq[3];
    float mu = S * (1.0f / Dd_);
    float var = Q * (1.0f / Dd_) - mu * mu;
    ls[0] = mu;
    lq[0] = rsqrtf(var + 1e-5f);
  }
  __syncthreads();
  const float mu = ls[0], rstd = lq[0];
  float4 g = *(const float4*)(gamma + t * 4);
  float4 be = *(const float4*)(beta + t * 4);
  bf16x4 ov;
  ov[0] = (bf16)((v.x - mu) * rstd * g.x + be.x);
  ov[1] = (bf16)((v.y - mu) * rstd * g.y + be.y);
  ov[2] = (bf16)((v.z - mu) * rstd * g.z + be.z);
  ov[3] = (bf16)((v.w - mu) * rstd * g.w + be.w);
  *(bf16x4*)(xn + row * Dd_ + t * 4) = ov;
}

// ---------- softmax: fp16 scores (two slabs) -> fp16 probs (UNSCALED), in place ----------
__global__ __launch_bounds__(256) void softmax16_k(f16* __restrict__ lo,
                                                   f16* __restrict__ hi) {
  const long row = blockIdx.x;
  const long z = row >> 11;
  f16* sr = (z < 4 ? lo + z * 4194304L : hi + (z - 4) * 4194304L) +
            (row & 2047) * (long)Ss_;
  const int t = threadIdx.x;
  f16x8 v = *(const f16x8*)(sr + t * 8);
  float f[8];
#pragma unroll
  for (int j = 0; j < 8; j++) f[j] = (float)v[j];
  float vm = f[0];
#pragma unroll
  for (int j = 1; j < 8; j++) vm = fmaxf(vm, f[j]);
  __shared__ float red[4];
#pragma unroll
  for (int o = 32; o > 0; o >>= 1) vm = fmaxf(vm, __shfl_xor(vm, o));
  const int wid = t >> 6;
  if ((t & 63) == 0) red[wid] = vm;
  __syncthreads();
  vm = fmaxf(fmaxf(red[0], red[1]), fmaxf(red[2], red[3]));
  float e[8], s = 0.f;
#pragma unroll
  for (int j = 0; j < 8; j++) { e[j] = __expf(f[j] - vm); s += e[j]; }
#pragma unroll
  for (int o = 32; o > 0; o >>= 1) s += __shfl_xor(s, o);
  __syncthreads();
  if ((t & 63) == 0) red[wid] = s;
  __syncthreads();
  s = red[0] + red[1] + red[2] + red[3];
  const float rs = 1.0f / s;  // 1/32 applied in PV epilogue
  f16x8 ov;
#pragma unroll
  for (int j = 0; j < 8; j++) ov[j] = (f16)(e[j] * rs);
  *(f16x8*)(sr + t * 8) = ov;
}

// ================= 256x256x64 pipelined 8-phase GEMM (C = A[M][K] * B[N][K]^T) ========
// 512 thr = 8 waves, wave tile 64x128 (wm=w>>1 in 0..3, wn=w&1). acc[4][8].
// b-quadrant double-slot (bA/bB) prefetched one phase ahead; A read once per K-tile
// with mid-phase lgkmcnt(4) (waits only the 8 A reads). One barrier per phase.
// Stage slots: P1:b1.B0(t1) P2:b1.B1 P3:b0.A0(t0+2) P4:b0.A1 P5:b0.B0 P6:b0.B1
// P7:b1.A0(t1+2) P8:b1.A1  — every stage >=2 phases after its half's last read.
// vmcnt(2) end-P3 (guarantees P1,P2 stages: buf1.B for P4/P5 reads; older implied),
// vmcnt(2) end-P7 (guarantees P3..P6: buf0 full for P8/P1' reads). Last iter: vmcnt(0).
template <int EPI, int DT>
__global__ __launch_bounds__(512, 2) void gemm8_k(
    const bf16* __restrict__ Ab, const bf16* __restrict__ Bbp, void* __restrict__ Cb,
    const float* __restrict__ bias, const float* __restrict__ resid,
    int K, int lda, int ldb, int ldc, long astr, long bstr, long cstr) {
  extern __shared__ bf16 L[];  // [buf2][A/B][half2][128*64] = 128 KiB
  const int t = threadIdx.x;
  const int lane = t & 63;
  const int w = t >> 6;
  const int wm = w >> 1, wn = w & 1;

  const int gx = gridDim.x;
  const int nwg = gx * gridDim.y;
  const int dd = blockIdx.y * gx + blockIdx.x;
  const int Lid = (dd & 7) * (nwg >> 3) + (dd >> 3);
  const int m0 = (Lid / gx) * 256;
  const int n0 = (Lid % gx) * 256;

  const long z = blockIdx.z;
  const bf16* A;
  if constexpr (EPI == EPI_AOS) {
    A = (z < 4 ? Ab + z * astr : (const bf16*)bias + (z - 4) * astr);
  } else if constexpr (EPI == EPI_RESID) {
    const long qo[4] = {0, 33554432, 50331648, 67108864};
    A = Ab + qo[m0 >> 12] - (long)(m0 & ~4095) * lda;
  } else {
    A = Ab + z * astr;
  }
  const bf16* Bp = Bbp + z * bstr;

  const int sr0 = (w * 2 + 0) * 8 + (lane >> 3);
  const int sr1 = (w * 2 + 1) * 8 + (lane >> 3);
  const int sc = 8 * ((lane & 7) ^ (lane >> 3));
  const bf16* gS[2][2][2];
  gS[0][0][0] = A + (long)(m0 + sr0) * lda + sc;
  gS[0][0][1] = A + (long)(m0 + sr1) * lda + sc;
  gS[0][1][0] = A + (long)(m0 + 128 + sr0) * lda + sc;
  gS[0][1][1] = A + (long)(m0 + 128 + sr1) * lda + sc;
  gS[1][0][0] = Bp + (long)(n0 + sr0) * ldb + sc;
  gS[1][0][1] = Bp + (long)(n0 + sr1) * ldb + sc;
  gS[1][1][0] = Bp + (long)(n0 + 128 + sr0) * ldb + sc;
  gS[1][1][1] = Bp + (long)(n0 + 128 + sr1) * ldb + sc;

#define STAGE(buf, isB, half, tau)                                              \
  do {                                                                          \
    gload16(gS[isB][half][0] + (long)(tau)*64,                                  \
            &L[(((buf)*2 + (isB)) * 2 + (half)) * 8192 + w * 1024]);            \
    gload16(gS[isB][half][1] + (long)(tau)*64,                                  \
            &L[(((buf)*2 + (isB)) * 2 + (half)) * 8192 + w * 1024 + 512]);      \
  } while (0)

  const int rA = lane & 15;
  const int kk0 = (lane >> 4) * 8;
  const int xorv = (rA & 7) * 8;
  // A section: rows wm*64..+63 live in half (wm>>1), local row (wm&1)*64+q*16+rA
  const int aRow = (wm & 1) * 64 + rA;
  const int aS0 = (0 * 4 + (wm >> 1)) * 8192, aS1 = (1 * 4 + (wm >> 1)) * 8192;
  // B section: wave's cols wn*128..+127 = half wn entirely
  const int bS0 = (0 * 4 + 2 + wn) * 8192, bS1 = (1 * 4 + 2 + wn) * 8192;

#define READ_A(ab)                                                              \
  _Pragma("unroll") for (int q_ = 0; q_ < 4; ++q_)                              \
  _Pragma("unroll") for (int ks_ = 0; ks_ < 2; ++ks_)                           \
      a[q_][ks_] = dsr128(&L[(ab) + (aRow + q_ * 16) * 64 +                     \
                             ((ks_ * 32 + kk0) ^ xorv)]);
#define READ_BQ(bb, nq, dst)                                                    \
  _Pragma("unroll") for (int q_ = 0; q_ < 2; ++q_)                              \
  _Pragma("unroll") for (int ks_ = 0; ks_ < 2; ++ks_)                           \
      dst[q_][ks_] = dsr128(&L[(bb) + ((nq)*32 + q_ * 16 + rA) * 64 +           \
                               ((ks_ * 32 + kk0) ^ xorv)]);
#define MM(av, bv, cv)                                                          \
  (DT ? __builtin_amdgcn_mfma_f32_16x16x32_f16(                                 \
            __builtin_bit_cast(f16x8, av), __builtin_bit_cast(f16x8, bv), cv,   \
            0, 0, 0)                                                            \
      : __builtin_amdgcn_mfma_f32_16x16x32_bf16(av, bv, cv, 0, 0, 0))
#define QMFMA(nq, bsel)                                                         \
  _Pragma("unroll") for (int ks_ = 0; ks_ < 2; ++ks_)                           \
  _Pragma("unroll") for (int m_ = 0; m_ < 4; ++m_)                              \
  _Pragma("unroll") for (int n_ = 0; n_ < 2; ++n_)                              \
      acc[m_][(nq)*2 + n_] =                                                    \
          MM(a[m_][ks_], bsel[n_][ks_], acc[m_][(nq)*2 + n_]);

  f32x4 acc[4][8] = {};
  bf16x8 a[4][2], bA[2][2], bB[2][2];

  // prologue: buf0 full (t=0) + buf1 A (t=1); buf1.B staged by P1/P2 of i=0.
  STAGE(0, 0, 0, 0); STAGE(0, 0, 1, 0); STAGE(0, 1, 0, 0); STAGE(0, 1, 1, 0);
  STAGE(1, 0, 0, 1); STAGE(1, 0, 1, 1);
  VMC(4);  // buf0 (8 oldest loads) landed
  BAR();
  READ_BQ(bS0, 0, bA);

  const int NI = K >> 7;  // 2 K-tiles per iteration
  for (int i = 0; i < NI; ++i) {
    const int t1 = 2 * i + 1;
    const bool nf = (i + 1 < NI);
    // P1 (tile t0, buf0): MFMA Q0 uses a(prev? -> this phase reads a), bA(bQ0)
    BAR(); LGKM0();
    READ_A(aS0);
    READ_BQ(bS0, 1, bB);
    STAGE(1, 1, 0, t1);
    LGKM4();  // wait the 8 A reads (in-order DS); 4 B reads may fly
    SCHED0(); SETP(1); QMFMA(0, bA); SETP(0);
    // P2: Q1 uses a,bB(bQ1); prefetch bQ2
    BAR(); LGKM0();
    READ_BQ(bS0, 2, bA);
    STAGE(1, 1, 1, t1);
    SCHED0(); SETP(1); QMFMA(1, bB); SETP(0);
    // P3: Q2 uses a,bA(bQ2); prefetch bQ3
    BAR(); LGKM0();
    READ_BQ(bS0, 3, bB);
    if (nf) STAGE(0, 0, 0, t1 + 1);
    SCHED0(); SETP(1); QMFMA(2, bA); SETP(0);
    if (nf) VMC(2); else VMC(0);   // buf1.B (P1,P2 stages) landed chip-wide after BAR
    // P4: Q3 uses a,bB(bQ3); prefetch next-tile bQ0 (buf1)
    BAR(); LGKM0();
    READ_BQ(bS1, 0, bA);
    if (nf) STAGE(0, 0, 1, t1 + 1);
    SCHED0(); SETP(1); QMFMA(3, bB); SETP(0);
    // P5 (tile t1, buf1)
    BAR(); LGKM0();
    READ_A(aS1);
    READ_BQ(bS1, 1, bB);
    if (nf) STAGE(0, 1, 0, t1 + 1);
    LGKM4();
    SCHED0(); SETP(1); QMFMA(0, bA); SETP(0);
    // P6
    BAR(); LGKM0();
    READ_BQ(bS1, 2, bA);
    if (nf) STAGE(0, 1, 1, t1 + 1);
    SCHED0(); SETP(1); QMFMA(1, bB); SETP(0);
    // P7
    BAR(); LGKM0();
    READ_BQ(bS1, 3, bB);
    if (nf) STAGE(1, 0, 0, t1 + 2);
    SCHED0(); SETP(1); QMFMA(2, bA); SETP(0);
    if (nf) VMC(2); else VMC(0);   // buf0 full (P3..P6 stages) landed
    // P8
    BAR(); LGKM0();
    if (nf) { READ_BQ(bS0, 0, bA); STAGE(1, 0, 1, t1 + 2); }
    SCHED0(); SETP(1); QMFMA(3, bB); SETP(0);
  }

  // epilogue: C/D layout col=lane&15, row=(lane>>4)*4+j; wave tile 64x128
  const int row0 = m0 + wm * 64;
  const int col0 = n0 + wn * 128;
  const int cl = lane & 15;
  const int rg = (lane >> 4) * 4;
#pragma unroll
  for (int mi = 0; mi < 4; mi++) {
#pragma unroll
    for (int ni = 0; ni < 8; ni++) {
#pragma unroll
      for (int j = 0; j < 4; j++) {
        const long gm = row0 + mi * 16 + rg + j;
        const int gn = col0 + ni * 16 + cl;
        float val = acc[mi][ni][j];
        if constexpr (EPI == EPI_QKV) {
          if (z < 2) {
            ((bf16*)Cb)[z * cstr + gm * ldc + gn] = (bf16)val;       // q,k
          } else {
            ((f16*)resid)[gm * (long)ldc + gn] = (f16)val;           // v rows fp16
          }
        } else if constexpr (EPI == EPI_F16) {
          ((f16*)Cb)[z * cstr + gm * ldc + gn] = (f16)val;
        } else if constexpr (EPI == EPI_AOS) {
          ((bf16*)Cb)[z * cstr + gm * ldc + gn] = (bf16)(val * 0.03125f);
        } else if constexpr (EPI == EPI_SWISH) {
          const long qoc[4] = {0, 33554432, 50331648, 67108864};
          bf16* hq = (bf16*)Cb + qoc[m0 >> 12];
          float hv = val + bias[gn];
          hq[(long)(gm & 4095) * ldc + gn] = (bf16)(hv / (1.0f + __expf(-hv)));
        } else {  // EPI_RESID
          ((float*)Cb)[gm * (long)ldc + gn] = val + bias[gn] + resid[gm * (long)ldc + gn];
        }
      }
    }
  }
#undef STAGE
#undef READ_A
#undef READ_BQ
#undef MM
#undef QMFMA
}

extern "C" void kernel_launch(void* const* d_in, const int* in_sizes, int n_in,
                              void* d_out, int out_size, void* d_ws, size_t ws_size,
                              hipStream_t stream) {
  const float* x  = (const float*)d_in[0];
  const float* g  = (const float*)d_in[1];
  const float* be = (const float*)d_in[2];
  const float* Wq = (const float*)d_in[3];
  const float* Wk = (const float*)d_in[4];
  const float* Wv = (const float*)d_in[5];
  const float* W1 = (const float*)d_in[6];
  const float* b1 = (const float*)d_in[7];
  const float* W2 = (const float*)d_in[8];
  const float* b2 = (const float*)d_in[9];

  hipFuncSetAttribute((const void*)&gemm8_k<EPI_QKV, 0>,
                      hipFuncAttributeMaxDynamicSharedMemorySize, 131072);
  hipFuncSetAttribute((const void*)&gemm8_k<EPI_F16, 0>,
                      hipFuncAttributeMaxDynamicSharedMemorySize, 131072);
  hipFuncSetAttribute((const void*)&gemm8_k<EPI_AOS, 1>,
                      hipFuncAttributeMaxDynamicSharedMemorySize, 131072);
  hipFuncSetAttribute((const void*)&gemm8_k<EPI_SWISH, 0>,
                      hipFuncAttributeMaxDynamicSharedMemorySize, 131072);
  hipFuncSetAttribute((const void*)&gemm8_k<EPI_RESID, 0>,
                      hipFuncAttributeMaxDynamicSharedMemorySize, 131072);

  char* ws = (char*)d_ws;
  bf16* xn        = (bf16*)(ws + 0);
  f16*  scores_lo = (f16*)(ws + 0);
  bf16* q         = (bf16*)(ws + 33554432);
  bf16* ao        = (bf16*)(ws + 33554432);
  bf16* kk        = (bf16*)(ws + 67108864);
  f16*  vT        = (f16*)(ws + 100663296);
  f16*  vrows     = (f16*)(ws + 134217728);
  f16*  scores_hi = (f16*)(ws + 134217728);
  bf16* wqT       = (bf16*)(ws + 167772160);
  bf16* w1T       = (bf16*)(ws + 174063616);
  bf16* w2T       = (bf16*)(ws + 182452224);

  tcast_k<<<dim3(32, 32), 256, 0, stream>>>(Wq, wqT, 1024, 1024);
  tcast_k<<<dim3(32, 32), 256, 0, stream>>>(Wk, wqT + 1048576, 1024, 1024);
  tcast_k<<<dim3(32, 32), 256, 0, stream>>>(Wv, wqT + 2097152, 1024, 1024);
  tcast_k<<<dim3(128, 32), 256, 0, stream>>>(W1, w1T, 1024, 4096);
  tcast_k<<<dim3(32, 128), 256, 0, stream>>>(W2, w2T, 4096, 1024);

  ln_k<<<16384, 256, 0, stream>>>(x, g, be, xn);

  // QKV: z=0,1 -> q,k bf16; z=2 -> v rows fp16 via resid ptr
  gemm8_k<EPI_QKV, 0><<<dim3(4, 64, 3), 512, 131072, stream>>>(
      xn, wqT, q, nullptr, (const float*)vrows, 1024, 1024, 1024, 1024,
      0L, 1048576L, 16777216L);

  tbf16_k<<<dim3(16, 32, 8), 256, 0, stream>>>(vrows, vT);

  gemm8_k<EPI_F16, 0><<<dim3(8, 8, 4), 512, 131072, stream>>>(
      q, kk, scores_lo, nullptr, nullptr,
      1024, 1024, 1024, 2048, 2097152L, 2097152L, 4194304L);
  gemm8_k<EPI_F16, 0><<<dim3(8, 8, 4), 512, 131072, stream>>>(
      q + 4L * 2097152, kk + 4L * 2097152, scores_hi, nullptr, nullptr,
      1024, 1024, 1024, 2048, 2097152L, 2097152L, 4194304L);

  softmax16_k<<<16384, 256, 0, stream>>>(scores_lo, scores_hi);

  // PV: single launch over all 8 batches; A slab-split inside kernel
  gemm8_k<EPI_AOS, 1><<<dim3(4, 8, 8), 512, 131072, stream>>>(
      (const bf16*)scores_lo, (const bf16*)vT, ao, (const float*)scores_hi, nullptr,
      2048, 2048, 2048, 1024, 4194304L, 2097152L, 2097152L);

  // MLP1: h (quartered) = swish(ao @ W1 + b1)
  gemm8_k<EPI_SWISH, 0><<<dim3(16, 64, 1), 512, 131072, stream>>>(
      ao, w1T, ws, b1, nullptr, 1024, 1024, 1024, 4096, 0L, 0L, 0L);
  // MLP2: out = h @ W2 + b2 + x
  gemm8_k<EPI_RESID, 0><<<dim3(4, 64, 1), 512, 131072, stream>>>(
      (const bf16*)ws, w2T, d_out, b2, x, 4096, 4096, 4096, 1024, 0L, 0L, 0L);
}

// Round 8
// 613.732 us; speedup vs baseline: 1.4985x; 1.4985x over previous
//
#include <hip/hip_runtime.h>

// EncoderBlock: B=8, S=2048, D=1024, H=4096, single-head attn (scale AFTER softmax),
// LN -> QKV -> scores -> softmax*(1/32) -> PV -> MLP(Swish) -> +residual.
// Round 8: 2-blocks-per-CU GEMM core. 128x128 tile, BK=64, 64KiB LDS dbuf, 4 waves,
// one barrier per K-tile; independent co-resident blocks overlap each other's stalls
// (m114 wave-level overlap) instead of asm-exact phase tuning. Non-GEMM parts = R6.
// WS = 190,840,832 B, overlay identical to R6.

#define Bb_ 8
#define Ss_ 2048
#define Dd_ 1024
#define Hh_ 4096

typedef __bf16 bf16;
typedef _Float16 f16;
typedef __attribute__((ext_vector_type(8))) __bf16 bf16x8;
typedef __attribute__((ext_vector_type(8))) _Float16 f16x8;
typedef __attribute__((ext_vector_type(4))) __bf16 bf16x4;
typedef __attribute__((ext_vector_type(4))) float f32x4;

enum { EPI_QKV = 0, EPI_F16 = 1, EPI_AOS = 2, EPI_SWISH = 3, EPI_RESID = 4 };

__device__ __forceinline__ void gload16(const bf16* g, bf16* l) {
  __builtin_amdgcn_global_load_lds(
      (const __attribute__((address_space(1))) void*)g,
      (__attribute__((address_space(3))) void*)l, 16, 0, 0);
}

typedef const __attribute__((address_space(3))) bf16 cl_bf16;
__device__ __forceinline__ bf16x8 dsr128(const bf16* p) {
  bf16x8 r;
  asm volatile("ds_read_b128 %0, %1" : "=v"(r) : "v"((cl_bf16*)p));
  return r;
}

#define BAR() __builtin_amdgcn_s_barrier()
#define LGKM0() asm volatile("s_waitcnt lgkmcnt(0)" ::: "memory")
#define VMC0() asm volatile("s_waitcnt vmcnt(0)" ::: "memory")
#define SCHED0() __builtin_amdgcn_sched_barrier(0)
#define SETP(x) __builtin_amdgcn_s_setprio(x)

// ---------- transpose-cast: W[K][N] f32 -> WT[N][K] bf16 ----------
__global__ __launch_bounds__(256) void tcast_k(const float* __restrict__ W,
                                               bf16* __restrict__ WT, int K, int N) {
  __shared__ float tile[32][33];
  const int tn0 = blockIdx.x * 32;
  const int tk0 = blockIdx.y * 32;
  const int t = threadIdx.x;
  const int c = t & 31;
  const int r4 = t >> 5;
#pragma unroll
  for (int i = 0; i < 4; i++) {
    int r = r4 + i * 8;
    tile[r][c] = W[(long)(tk0 + r) * N + (tn0 + c)];
  }
  __syncthreads();
#pragma unroll
  for (int i = 0; i < 4; i++) {
    int r = r4 + i * 8;
    WT[(long)(tn0 + r) * K + (tk0 + c)] = (bf16)tile[c][r];
  }
}

// ---------- fp16 transpose: v[z][2048][1024] -> vT[z][1024][2048] ----------
__global__ __launch_bounds__(256) void tbf16_k(const f16* __restrict__ V,
                                               f16* __restrict__ VT) {
  __shared__ f16 tile[64][72];
  const long z = blockIdx.z;
  const int n0 = blockIdx.x * 64;
  const int k0 = blockIdx.y * 64;
  const int t = threadIdx.x;
  const int r = t >> 3;
  const int c = (t & 7) * 8;
  const f16* Vb = V + z * (long)(Ss_ * Dd_);
  f16* VTb = VT + z * (long)(Dd_ * Ss_);
#pragma unroll
  for (int i = 0; i < 2; i++)
    *(f16x8*)&tile[r + i * 32][c] =
        *(const f16x8*)(Vb + (long)(k0 + r + i * 32) * Dd_ + n0 + c);
  __syncthreads();
#pragma unroll
  for (int i = 0; i < 2; i++) {
    const int n = r + i * 32;
    f16x8 ov;
#pragma unroll
    for (int j = 0; j < 8; j++) ov[j] = tile[c + j][n];
    *(f16x8*)(VTb + (long)(n0 + n) * Ss_ + k0 + c) = ov;
  }
}

// ---------- LayerNorm: x[row][1024] f32 -> xn bf16 ----------
__global__ __launch_bounds__(256) void ln_k(const float* __restrict__ x,
                                            const float* __restrict__ gamma,
                                            const float* __restrict__ beta,
                                            bf16* __restrict__ xn) {
  const long row = blockIdx.x;
  const float* xr = x + row * Dd_;
  const int t = threadIdx.x;
  float4 v = *(const float4*)(xr + t * 4);
  float s = v.x + v.y + v.z + v.w;
  float sq = v.x * v.x + v.y * v.y + v.z * v.z + v.w * v.w;
#pragma unroll
  for (int o = 32; o > 0; o >>= 1) {
    s += __shfl_down(s, o);
    sq += __shfl_down(sq, o);
  }
  __shared__ float ls[4], lq[4];
  const int wid = t >> 6;
  if ((t & 63) == 0) { ls[wid] = s; lq[wid] = sq; }
  __syncthreads();
  if (t == 0) {
    float S = ls[0] + ls[1] + ls[2] + ls[3];
    float Q = lq[0] + lq[1] + lq[2] + lq[3];
    float mu = S * (1.0f / Dd_);
    float var = Q * (1.0f / Dd_) - mu * mu;
    ls[0] = mu;
    lq[0] = rsqrtf(var + 1e-5f);
  }
  __syncthreads();
  const float mu = ls[0], rstd = lq[0];
  float4 g = *(const float4*)(gamma + t * 4);
  float4 be = *(const float4*)(beta + t * 4);
  bf16x4 ov;
  ov[0] = (bf16)((v.x - mu) * rstd * g.x + be.x);
  ov[1] = (bf16)((v.y - mu) * rstd * g.y + be.y);
  ov[2] = (bf16)((v.z - mu) * rstd * g.z + be.z);
  ov[3] = (bf16)((v.w - mu) * rstd * g.w + be.w);
  *(bf16x4*)(xn + row * Dd_ + t * 4) = ov;
}

// ---------- softmax: fp16 scores (two slabs) -> fp16 probs (UNSCALED), in place ----------
__global__ __launch_bounds__(256) void softmax16_k(f16* __restrict__ lo,
                                                   f16* __restrict__ hi) {
  const long row = blockIdx.x;
  const long z = row >> 11;
  f16* sr = (z < 4 ? lo + z * 4194304L : hi + (z - 4) * 4194304L) +
            (row & 2047) * (long)Ss_;
  const int t = threadIdx.x;
  f16x8 v = *(const f16x8*)(sr + t * 8);
  float f[8];
#pragma unroll
  for (int j = 0; j < 8; j++) f[j] = (float)v[j];
  float vm = f[0];
#pragma unroll
  for (int j = 1; j < 8; j++) vm = fmaxf(vm, f[j]);
  __shared__ float red[4];
#pragma unroll
  for (int o = 32; o > 0; o >>= 1) vm = fmaxf(vm, __shfl_xor(vm, o));
  const int wid = t >> 6;
  if ((t & 63) == 0) red[wid] = vm;
  __syncthreads();
  vm = fmaxf(fmaxf(red[0], red[1]), fmaxf(red[2], red[3]));
  float e[8], s = 0.f;
#pragma unroll
  for (int j = 0; j < 8; j++) { e[j] = __expf(f[j] - vm); s += e[j]; }
#pragma unroll
  for (int o = 32; o > 0; o >>= 1) s += __shfl_xor(s, o);
  __syncthreads();
  if ((t & 63) == 0) red[wid] = s;
  __syncthreads();
  s = red[0] + red[1] + red[2] + red[3];
  const float rs = 1.0f / s;  // 1/32 applied in PV epilogue
  f16x8 ov;
#pragma unroll
  for (int j = 0; j < 8; j++) ov[j] = (f16)(e[j] * rs);
  *(f16x8*)(sr + t * 8) = ov;
}

// ========== 128x128xK GEMM, BK=64, dbuf 64KiB LDS, 4 waves, 2 blocks/CU ==========
// C = A[M][K] * B[N][K]^T. DT=0 bf16 MFMA, DT=1 f16 MFMA (bytes staged either way).
// LDS: L[buf2][op2][128*64] swizzled: (r,k) at elem r*64 + (k ^ ((r&7)*8));
// staged via pre-swizzled GLOBAL source + linear gload_lds dest (rule 21).
// Per K-tile t:  STAGE(t+1 -> buf^1)  ||  READS(t, buf)  ; lgkm0 ; 32 MFMA ;
//                vmcnt(0) [own 8 stages; slack = reads+MFMA] ; s_barrier.
// Hazards: stage(t+1) overwrites tile t-1's buf — all waves lgkm0'd those reads
// before the prior barrier. vmcnt(0)+barrier makes stage completion collective
// before next phase's reads. lgkm0 is wave-local (each wave consumes own reads).
template <int EPI, int DT>
__global__ __launch_bounds__(256, 2) void gemmdb_k(
    const bf16* __restrict__ Ab, const bf16* __restrict__ Bbp, void* __restrict__ Cb,
    const float* __restrict__ bias, const float* __restrict__ resid,
    int K, int lda, int ldb, int ldc, long astr, long bstr, long cstr) {
  extern __shared__ bf16 L[];  // 2*2*8192 elems = 64 KiB
  const int t = threadIdx.x;
  const int lane = t & 63;
  const int w = t >> 6;             // 0..3
  const int wm = w >> 1, wn = w & 1;

  // bijective XCD swizzle (all grids have (gx*gy)%8==0)
  const int gx = gridDim.x;
  const int nwg = gx * gridDim.y;
  const int dd = blockIdx.y * gx + blockIdx.x;
  const int Lid = (dd & 7) * (nwg >> 3) + (dd >> 3);
  const int m0 = (Lid / gx) * 128;
  const int n0 = (Lid % gx) * 128;

  const long z = blockIdx.z;
  const bf16* A;
  if constexpr (EPI == EPI_AOS) {
    A = (z < 4 ? Ab + z * astr : (const bf16*)bias + (z - 4) * astr);
  } else if constexpr (EPI == EPI_RESID) {
    const long qo[4] = {0, 33554432, 50331648, 67108864};  // h quarters (elem offs)
    A = Ab + qo[m0 >> 12] - (long)(m0 & ~4095) * lda;
  } else {
    A = Ab + z * astr;
  }
  const bf16* Bp = Bbp + z * bstr;

  // staging: 128 rows -> 16 chunks of 8 rows (1KB each); wave w stages A,B chunks 4w..4w+3.
  // lane l -> row chunk*8 + (l>>3); pre-swizzled source col = 8*((l&7)^(l>>3)).
  const int lrow = lane >> 3;
  const int sc = 8 * ((lane & 7) ^ lrow);
  const bf16* gA[4];
  const bf16* gB[4];
#pragma unroll
  for (int j = 0; j < 4; ++j) {
    const int r = (w * 4 + j) * 8 + lrow;
    gA[j] = A + (long)(m0 + r) * lda + sc;
    gB[j] = Bp + (long)(n0 + r) * ldb + sc;
  }

#define STAGE(buf, tau)                                                          \
  do {                                                                           \
    _Pragma("unroll") for (int j_ = 0; j_ < 4; ++j_)                             \
        gload16(gA[j_] + (long)(tau) * 64,                                       \
                &L[((buf)*2 + 0) * 8192 + (w * 4 + j_) * 512]);                  \
    _Pragma("unroll") for (int j_ = 0; j_ < 4; ++j_)                             \
        gload16(gB[j_] + (long)(tau) * 64,                                       \
                &L[((buf)*2 + 1) * 8192 + (w * 4 + j_) * 512]);                  \
  } while (0)

  // fragment reads: A rows wm*64.., B rows wn*64..; 16 dsr128 per K-tile
  const int rA = lane & 15;
  const int kk0 = (lane >> 4) * 8;
  const int xorv = (rA & 7) * 8;

#define READ_ALL(ab, bb)                                                         \
  _Pragma("unroll") for (int q_ = 0; q_ < 4; ++q_)                               \
  _Pragma("unroll") for (int ks_ = 0; ks_ < 2; ++ks_) {                          \
    a[q_][ks_] = dsr128(&L[(ab) + (wm * 64 + q_ * 16 + rA) * 64 +                \
                           ((ks_ * 32 + kk0) ^ xorv)]);                          \
    b[q_][ks_] = dsr128(&L[(bb) + (wn * 64 + q_ * 16 + rA) * 64 +                \
                           ((ks_ * 32 + kk0) ^ xorv)]);                          \
  }
#define MM(av, bv, cv)                                                           \
  (DT ? __builtin_amdgcn_mfma_f32_16x16x32_f16(                                  \
            __builtin_bit_cast(f16x8, av), __builtin_bit_cast(f16x8, bv), cv,    \
            0, 0, 0)                                                             \
      : __builtin_amdgcn_mfma_f32_16x16x32_bf16(av, bv, cv, 0, 0, 0))

  f32x4 acc[4][4] = {};
  bf16x8 a[4][2], b[4][2];

  // prologue: stage tile 0 into buf0
  STAGE(0, 0);
  VMC0();
  BAR();

  const int NT = K >> 6;
  for (int tt = 0; tt < NT; ++tt) {
    const int cur = tt & 1;
    const int ab = (cur * 2 + 0) * 8192;
    const int bb = (cur * 2 + 1) * 8192;
    const bool nf = (tt + 1 < NT);
    if (nf) STAGE(cur ^ 1, tt + 1);
    READ_ALL(ab, bb);
    LGKM0();
    SCHED0();
    SETP(1);
#pragma unroll
    for (int ks = 0; ks < 2; ++ks)
#pragma unroll
      for (int q = 0; q < 4; ++q)
#pragma unroll
        for (int p = 0; p < 4; ++p)
          acc[q][p] = MM(a[q][ks], b[p][ks], acc[q][p]);
    SETP(0);
    if (nf) VMC0();  // own 8 stages of t+1 landed; slack = reads+MFMA above
    BAR();
  }

  // epilogue: C/D layout col=lane&15, row=(lane>>4)*4+j
  const int row0 = m0 + wm * 64;
  const int col0 = n0 + wn * 64;
  const int cl = lane & 15;
  const int rg = (lane >> 4) * 4;
#pragma unroll
  for (int mi = 0; mi < 4; mi++) {
#pragma unroll
    for (int ni = 0; ni < 4; ni++) {
#pragma unroll
      for (int j = 0; j < 4; j++) {
        const long gm = row0 + mi * 16 + rg + j;
        const int gn = col0 + ni * 16 + cl;
        float val = acc[mi][ni][j];
        if constexpr (EPI == EPI_QKV) {
          if (z < 2) {
            ((bf16*)Cb)[z * cstr + gm * ldc + gn] = (bf16)val;   // q,k bf16
          } else {
            ((f16*)resid)[gm * (long)ldc + gn] = (f16)val;       // v rows fp16
          }
        } else if constexpr (EPI == EPI_F16) {
          ((f16*)Cb)[z * cstr + gm * ldc + gn] = (f16)val;
        } else if constexpr (EPI == EPI_AOS) {
          ((bf16*)Cb)[z * cstr + gm * ldc + gn] = (bf16)(val * 0.03125f);
        } else if constexpr (EPI == EPI_SWISH) {
          const long qoc[4] = {0, 33554432, 50331648, 67108864};
          bf16* hq = (bf16*)Cb + qoc[m0 >> 12];
          float hv = val + bias[gn];
          hq[(long)(gm & 4095) * ldc + gn] = (bf16)(hv / (1.0f + __expf(-hv)));
        } else {  // EPI_RESID
          ((float*)Cb)[gm * (long)ldc + gn] = val + bias[gn] + resid[gm * (long)ldc + gn];
        }
      }
    }
  }
#undef STAGE
#undef READ_ALL
#undef MM
}

extern "C" void kernel_launch(void* const* d_in, const int* in_sizes, int n_in,
                              void* d_out, int out_size, void* d_ws, size_t ws_size,
                              hipStream_t stream) {
  const float* x  = (const float*)d_in[0];
  const float* g  = (const float*)d_in[1];
  const float* be = (const float*)d_in[2];
  const float* Wq = (const float*)d_in[3];
  const float* Wk = (const float*)d_in[4];
  const float* Wv = (const float*)d_in[5];
  const float* W1 = (const float*)d_in[6];
  const float* b1 = (const float*)d_in[7];
  const float* W2 = (const float*)d_in[8];
  const float* b2 = (const float*)d_in[9];

  hipFuncSetAttribute((const void*)&gemmdb_k<EPI_QKV, 0>,
                      hipFuncAttributeMaxDynamicSharedMemorySize, 65536);
  hipFuncSetAttribute((const void*)&gemmdb_k<EPI_F16, 0>,
                      hipFuncAttributeMaxDynamicSharedMemorySize, 65536);
  hipFuncSetAttribute((const void*)&gemmdb_k<EPI_AOS, 1>,
                      hipFuncAttributeMaxDynamicSharedMemorySize, 65536);
  hipFuncSetAttribute((const void*)&gemmdb_k<EPI_SWISH, 0>,
                      hipFuncAttributeMaxDynamicSharedMemorySize, 65536);
  hipFuncSetAttribute((const void*)&gemmdb_k<EPI_RESID, 0>,
                      hipFuncAttributeMaxDynamicSharedMemorySize, 65536);

  // ---- workspace overlay (bytes); identical to R6 ----
  char* ws = (char*)d_ws;
  bf16* xn        = (bf16*)(ws + 0);
  f16*  scores_lo = (f16*)(ws + 0);            // z=0..3 after xn dies
  bf16* q         = (bf16*)(ws + 33554432);
  bf16* ao        = (bf16*)(ws + 33554432);    // after q dies
  bf16* kk        = (bf16*)(ws + 67108864);
  f16*  vT        = (f16*)(ws + 100663296);
  f16*  vrows     = (f16*)(ws + 134217728);
  f16*  scores_hi = (f16*)(ws + 134217728);    // z=4..7 after vrows dies
  bf16* wqT       = (bf16*)(ws + 167772160);
  bf16* w1T       = (bf16*)(ws + 174063616);
  bf16* w2T       = (bf16*)(ws + 182452224);
  // h quarters at byte offsets {0, 67108864, 100663296, 134217728} (EPI_SWISH/RESID).

  tcast_k<<<dim3(32, 32), 256, 0, stream>>>(Wq, wqT, 1024, 1024);
  tcast_k<<<dim3(32, 32), 256, 0, stream>>>(Wk, wqT + 1048576, 1024, 1024);
  tcast_k<<<dim3(32, 32), 256, 0, stream>>>(Wv, wqT + 2097152, 1024, 1024);
  tcast_k<<<dim3(128, 32), 256, 0, stream>>>(W1, w1T, 1024, 4096);
  tcast_k<<<dim3(32, 128), 256, 0, stream>>>(W2, w2T, 4096, 1024);

  ln_k<<<16384, 256, 0, stream>>>(x, g, be, xn);

  // QKV: z=0,1 -> q,k bf16; z=2 -> v rows fp16 via resid ptr
  gemmdb_k<EPI_QKV, 0><<<dim3(8, 128, 3), 256, 65536, stream>>>(
      xn, wqT, q, nullptr, (const float*)vrows, 1024, 1024, 1024, 1024,
      0L, 1048576L, 16777216L);

  tbf16_k<<<dim3(16, 32, 8), 256, 0, stream>>>(vrows, vT);

  // scores: two fp16 slabs
  gemmdb_k<EPI_F16, 0><<<dim3(16, 16, 4), 256, 65536, stream>>>(
      q, kk, scores_lo, nullptr, nullptr,
      1024, 1024, 1024, 2048, 2097152L, 2097152L, 4194304L);
  gemmdb_k<EPI_F16, 0><<<dim3(16, 16, 4), 256, 65536, stream>>>(
      q + 4L * 2097152, kk + 4L * 2097152, scores_hi, nullptr, nullptr,
      1024, 1024, 1024, 2048, 2097152L, 2097152L, 4194304L);

  softmax16_k<<<16384, 256, 0, stream>>>(scores_lo, scores_hi);

  // PV: single launch over all 8 batches; A slab-split inside kernel (f16 MFMA)
  gemmdb_k<EPI_AOS, 1><<<dim3(8, 16, 8), 256, 65536, stream>>>(
      (const bf16*)scores_lo, (const bf16*)vT, ao, (const float*)scores_hi, nullptr,
      2048, 2048, 2048, 1024, 4194304L, 2097152L, 2097152L);

  // MLP1: h (quartered) = swish(ao @ W1 + b1)
  gemmdb_k<EPI_SWISH, 0><<<dim3(32, 128, 1), 256, 65536, stream>>>(
      ao, w1T, ws, b1, nullptr, 1024, 1024, 1024, 4096, 0L, 0L, 0L);
  // MLP2: out = h @ W2 + b2 + x (A from h quarters)
  gemmdb_k<EPI_RESID, 0><<<dim3(8, 128, 1), 256, 65536, stream>>>(
      (const bf16*)ws, w2T, d_out, b2, x, 4096, 4096, 4096, 1024, 0L, 0L, 0L);
}